// Round 10
// baseline (222.144 us; speedup 1.0000x reference)
//
#include <hip/hip_runtime.h>

#define L 4096
#define HH 64
#define WW 64
#define DM 96
#define DI 192
#define DSTATE 16
#define DTR 6
#define NC 38   // DTR + 2*DSTATE
#define NCP 40  // padded x_dbl / pwT row stride (16B-aligned float4 groups)
#define KD 4
#define CH1 16        // xs1 / scan2 chunk
#define NCH1 256      // L / CH1
#define CH3 32        // scan3 chunk
#define NCH3 128      // L / CH3
#define NS 8          // states per thread (DSTATE/2)
#define TL 8          // l-tile for in_proj
#define LOG2E 1.44269504f
#define LN2   0.69314718f

__device__ __forceinline__ float silu_f(float v){ return v / (1.f + __expf(-v)); }
__device__ __forceinline__ float softplus_f(float v){
  float a = fabsf(v);
  float e = exp2f(-a * LOG2E);
  return fmaxf(v, 0.f) + LN2 * log2f(1.f + e);
}
// scan index l -> row-major spatial index for direction k
__device__ __forceinline__ int spat(int k, int l){
  int ll = (k & 2) ? (L - 1 - l) : l;
  return (k & 1) ? (((ll & 63) << 6) | (ll >> 6)) : ll;
}

// ---------------- Kernel 0: weight transposes (+ pwT pad zero) ----------------
__global__ void k_prep(const float* __restrict__ ipw, const float* __restrict__ pw,
                       const float* __restrict__ ow,
                       float* __restrict__ ipwT, float* __restrict__ pwT,
                       float* __restrict__ owT){
  int i = blockIdx.x * 256 + threadIdx.x;
  if (i < 384*DM){ int o = i / DM, c = i % DM; ipwT[c*384 + o] = ipw[i]; }
  int j = i - 384*DM;
  if (j >= 0 && j < KD*NC*DI){
    int k = j / (NC*DI); int r = j % (NC*DI); int c = r / DI, d = r % DI;
    pwT[(k*DI + d)*NCP + c] = pw[j];          // padded stride 40
  }
  int m = i - 384*DM - KD*NC*DI;
  if (m >= 0 && m < DM*DI){ int o = m / DI, d = m % DI; owT[d*DM + o] = ow[m]; }
  int p = m - DM*DI;
  if (p >= 0 && p < KD*DI*2){                 // zero the pad columns 38,39
    int kd = p >> 1, q = p & 1;
    pwT[kd*NCP + NC + q] = 0.f;
  }
}

// ---------------- Kernel 1: in_proj -> x_ , silu(z) ----------------
__global__ void k_inproj(const float* __restrict__ x, const float* __restrict__ wT,
                         float* __restrict__ xo, float* __restrict__ sz){
  int l0 = blockIdx.x * TL;          // grid = 512
  int t  = threadIdx.x;              // 384 threads
  __shared__ float xl[TL][DM];
  for (int j = t; j < TL*DM; j += 384) xl[j / DM][j % DM] = x[l0*DM + j];
  __syncthreads();
  float acc[TL];
  #pragma unroll
  for (int i = 0; i < TL; i++) acc[i] = 0.f;
  #pragma unroll 4
  for (int c = 0; c < DM; c++){
    float wv = wT[c*384 + t];
    #pragma unroll
    for (int i = 0; i < TL; i++) acc[i] += xl[i][c] * wv;
  }
  if (t < DI){
    #pragma unroll
    for (int i = 0; i < TL; i++) xo[(l0 + i)*DI + t] = acc[i];
  } else {
    int z = t - DI;
    #pragma unroll
    for (int i = 0; i < TL; i++) sz[(l0 + i)*DI + z] = silu_f(acc[i]);
  }
}

// ---------------- Kernel 2: depthwise 3x3 conv + bias + silu -> xc ----------------
__global__ void k_conv(const float* __restrict__ xi, const float* __restrict__ cw,
                       const float* __restrict__ cb, float* __restrict__ xc){
  int idx = blockIdx.x * blockDim.x + threadIdx.x;
  if (idx >= L*DI) return;
  int d = idx % DI, l = idx / DI;
  int h = l >> 6, w = l & 63;
  float acc = cb[d];
  #pragma unroll
  for (int dy = 0; dy < 3; dy++){
    int hh = h + dy - 1;
    if (hh < 0 || hh >= HH) continue;
    #pragma unroll
    for (int dx = 0; dx < 3; dx++){
      int ww = w + dx - 1;
      if (ww < 0 || ww >= WW) continue;
      acc += xi[(hh*WW + ww)*DI + d] * cw[(dy*3 + dx)*DI + d];
    }
  }
  xc[idx] = silu_f(acc);
}

// ------- Kernel 3: FUSED x_dbl + scan pass 1; CH1=16, 1024 blocks, 384 thr -------
// matvec: thread (i, cg, half) does a 96-MAC half-dot; halves combine via shfl_xor(1).
__global__ __launch_bounds__(384) void k_xs1(
    const float* __restrict__ xc, const float* __restrict__ pwT,
    const float* __restrict__ dtw, const float* __restrict__ dtb,
    const float* __restrict__ alogs,
    float* __restrict__ xdbp, float* __restrict__ Pb, float* __restrict__ Gb){
  int k  = blockIdx.x >> 8;   // grid = 4*256
  int ch = blockIdx.x & 255;
  int l0 = ch * CH1;
  int t  = threadIdx.x;
  __shared__ float sxc[CH1][DI + 1];   // pad: distinct i -> distinct banks
  __shared__ float sdt[CH1][8];
  __shared__ float sB[CH1][16];
  for (int j = t; j < CH1*DI; j += 384){
    int i = j / DI, dd = j % DI;
    sxc[i][dd] = xc[spat(k, l0 + i)*DI + dd];   // coalesced 192-float rows
  }
  __syncthreads();
  // x_dbl tile: 16 rows x 40 cols (pad zeroed); (i, cg, half) -> 4 outputs, half-dot
  if (t < 320){
    int i = t / 20, r = t % 20, cg = r >> 1, half2 = r & 1;
    const float4* pr4 = (const float4*)(pwT + k*DI*NCP) + cg;
    float4 a = make_float4(0.f, 0.f, 0.f, 0.f);
    int dd0 = half2 * 96;
    #pragma unroll 8
    for (int q = 0; q < 96; q++){
      int dd = dd0 + q;
      float v = sxc[i][dd];
      float4 w = pr4[dd*10];
      a.x += v*w.x; a.y += v*w.y; a.z += v*w.z; a.w += v*w.w;
    }
    a.x += __shfl_xor(a.x, 1);
    a.y += __shfl_xor(a.y, 1);
    a.z += __shfl_xor(a.z, 1);
    a.w += __shfl_xor(a.w, 1);
    if (half2 == 0){
      *(float4*)&xdbp[(size_t)(k*L + l0 + i)*NCP + cg*4] = a;
      float av[4] = {a.x, a.y, a.z, a.w};
      int c0 = cg*4;
      #pragma unroll
      for (int q = 0; q < 4; q++){
        int c = c0 + q;
        if (c < DTR) sdt[i][c] = av[q];
        else if (c < DTR + DSTATE) sB[i][c - DTR] = av[q];
      }
    }
  }
  int d = t >> 1, half = t & 1;
  float wr[DTR];
  #pragma unroll
  for (int r = 0; r < DTR; r++) wr[r] = dtw[(k*DI + d)*DTR + r];
  float bb = dtb[k*DI + d];
  float A2[NS];
  const float* ap = alogs + (k*DI + d)*DSTATE + half*NS;
  #pragma unroll
  for (int j = 0; j < NS; j++) A2[j] = -__expf(ap[j]) * LOG2E;
  float P[NS], G[NS];
  #pragma unroll
  for (int j = 0; j < NS; j++){ P[j] = 1.f; G[j] = 0.f; }
  __syncthreads();
  #pragma unroll 8
  for (int i = 0; i < CH1; i++){
    float xval = sxc[i][d];
    float dv = bb;
    #pragma unroll
    for (int r = 0; r < DTR; r++) dv += wr[r] * sdt[i][r];
    dv = softplus_f(dv);
    float tv = dv * xval;
    float4 b0 = *(const float4*)&sB[i][half*8];
    float4 b1 = *(const float4*)&sB[i][half*8 + 4];
    float Bv[NS] = {b0.x,b0.y,b0.z,b0.w,b1.x,b1.y,b1.z,b1.w};
    #pragma unroll
    for (int j = 0; j < NS; j++){
      float dA = exp2f(dv * A2[j]);
      G[j] = dA * G[j] + tv * Bv[j];
      P[j] *= dA;
    }
  }
  size_t base = (size_t)(k*NCH1 + ch)*DI*DSTATE + t*NS;
  ((float4*)(Pb + base))[0] = make_float4(P[0],P[1],P[2],P[3]);
  ((float4*)(Pb + base))[1] = make_float4(P[4],P[5],P[6],P[7]);
  ((float4*)(Gb + base))[0] = make_float4(G[0],G[1],G[2],G[3]);
  ((float4*)(Gb + base))[1] = make_float4(G[4],G[5],G[6],G[7]);
}

// ---------------- Kernel 4: scan pass 2 — Hillis-Steele over 256 chunks ----------------
__global__ void k_scan2(const float* __restrict__ Pb, const float* __restrict__ Gb,
                        float* __restrict__ Hin){
  int k = blockIdx.x / DI;
  int d = blockIdx.x % DI;
  int c = threadIdx.x;   // chunk id, 256 threads
  float P[DSTATE], G[DSTATE];
  const float* Pp = Pb + ((size_t)(k*NCH1 + c)*DI + d)*DSTATE;
  const float* Gp = Gb + ((size_t)(k*NCH1 + c)*DI + d)*DSTATE;
  #pragma unroll
  for (int n = 0; n < DSTATE; n++){ P[n] = Pp[n]; G[n] = Gp[n]; }
  __shared__ float sP[NCH1][DSTATE + 1];
  __shared__ float sG[NCH1][DSTATE + 1];
  for (int off = 1; off < NCH1; off <<= 1){
    #pragma unroll
    for (int n = 0; n < DSTATE; n++){ sP[c][n] = P[n]; sG[c][n] = G[n]; }
    __syncthreads();
    if (c >= off){
      #pragma unroll
      for (int n = 0; n < DSTATE; n++){
        float a1 = sP[c - off][n], b1 = sG[c - off][n];
        G[n] = P[n]*b1 + G[n];
        P[n] = P[n]*a1;
      }
    }
    __syncthreads();
  }
  #pragma unroll
  for (int n = 0; n < DSTATE; n++) sG[c][n] = G[n];
  __syncthreads();
  float* Hp = Hin + ((size_t)(k*NCH1 + c)*DI + d)*DSTATE;
  #pragma unroll
  for (int n = 0; n < DSTATE; n++) Hp[n] = (c == 0) ? 0.f : sG[c - 1][n];
}

// ---------------- Kernel 5: scan pass 3 — CH3=32 replay, emit oyT[l][k][d] ----------------
__global__ __launch_bounds__(384) void k_scan3(
    const float* __restrict__ xdbp, const float* __restrict__ xc,
    const float* __restrict__ dtw, const float* __restrict__ dtb,
    const float* __restrict__ alogs, const float* __restrict__ Dsv,
    const float* __restrict__ Hin, float* __restrict__ oyT){
  int k  = blockIdx.x >> 7;   // grid = 4*128
  int ch = blockIdx.x & 127;
  int l0 = ch * CH3;
  int t  = threadIdx.x;
  int d  = t >> 1, half = t & 1;
  __shared__ float sdt[CH3][8];
  __shared__ float sB[CH3][16];
  __shared__ float sC[CH3][16];
  __shared__ float sxc[CH3][DI];
  for (int j = t; j < CH3*NCP; j += 384){
    int i = j / NCP, c = j % NCP;
    float v = xdbp[(size_t)(k*L + l0)*NCP + j];   // coalesced padded rows
    if (c < DTR) sdt[i][c] = v;
    else if (c < DTR + DSTATE) sB[i][c - DTR] = v;
    else if (c < NC) sC[i][c - DTR - DSTATE] = v;
  }
  for (int j = t; j < CH3*DI; j += 384){
    int i = j / DI, dd = j % DI;
    sxc[i][dd] = xc[spat(k, l0 + i)*DI + dd];
  }
  float wr[DTR];
  #pragma unroll
  for (int r = 0; r < DTR; r++) wr[r] = dtw[(k*DI + d)*DTR + r];
  float bb = dtb[k*DI + d];
  float A2[NS];
  const float* ap = alogs + (k*DI + d)*DSTATE + half*NS;
  #pragma unroll
  for (int j = 0; j < NS; j++) A2[j] = -__expf(ap[j]) * LOG2E;
  float h[NS];
  // chunk-entry state: CH3 chunk ch == CH1 chunk 2*ch
  size_t hbase = (size_t)(k*NCH1 + 2*ch)*DI*DSTATE + t*NS;
  float4 h0 = ((const float4*)(Hin + hbase))[0];
  float4 h1 = ((const float4*)(Hin + hbase))[1];
  h[0]=h0.x; h[1]=h0.y; h[2]=h0.z; h[3]=h0.w;
  h[4]=h1.x; h[5]=h1.y; h[6]=h1.z; h[7]=h1.w;
  float Dv = Dsv[k*DI + d];
  __syncthreads();
  #pragma unroll 8
  for (int i = 0; i < CH3; i++){
    float xval = sxc[i][d];
    float dv = bb;
    #pragma unroll
    for (int r = 0; r < DTR; r++) dv += wr[r] * sdt[i][r];
    dv = softplus_f(dv);
    float tv = dv * xval;
    float4 b0 = *(const float4*)&sB[i][half*8];
    float4 b1 = *(const float4*)&sB[i][half*8 + 4];
    float4 c0 = *(const float4*)&sC[i][half*8];
    float4 c1 = *(const float4*)&sC[i][half*8 + 4];
    float Bv[NS] = {b0.x,b0.y,b0.z,b0.w,b1.x,b1.y,b1.z,b1.w};
    float Cv[NS] = {c0.x,c0.y,c0.z,c0.w,c1.x,c1.y,c1.z,c1.w};
    float y = (half == 0) ? Dv * xval : 0.f;
    #pragma unroll
    for (int j = 0; j < NS; j++){
      float dA = exp2f(dv * A2[j]);
      h[j] = dA * h[j] + tv * Bv[j];
      y += h[j] * Cv[j];
    }
    y += __shfl_xor(y, 1);
    if (half == 0) oyT[(size_t)(l0 + i)*KD*DI + k*DI + d] = y;
  }
}

// ---------------- Kernel 6: k-sum + LayerNorm + silu(z)*y + out proj ----------------
__global__ void k_final(const float* __restrict__ oyT, const float* __restrict__ sz,
                        const float* __restrict__ g, const float* __restrict__ b,
                        const float* __restrict__ owT, float* __restrict__ out){
  int l = blockIdx.x, t = threadIdx.x;  // 192 threads
  __shared__ float ym[DI];
  __shared__ float part[DI];
  __shared__ float red[6];
  float y = 0.f;
  #pragma unroll
  for (int k = 0; k < KD; k++) y += oyT[(size_t)l*KD*DI + k*DI + t];
  float s = y, s2 = y*y;
  #pragma unroll
  for (int off = 32; off; off >>= 1){ s += __shfl_down(s, off); s2 += __shfl_down(s2, off); }
  int wave = t >> 6, lane = t & 63;
  if (lane == 0){ red[wave] = s; red[3 + wave] = s2; }
  __syncthreads();
  float S  = red[0] + red[1] + red[2];
  float SQ = red[3] + red[4] + red[5];
  float mu  = S * (1.f/DI);
  float var = SQ * (1.f/DI) - mu*mu;
  float yn = (y - mu) * rsqrtf(var + 1e-5f) * g[t] + b[t];
  ym[t] = yn * sz[(size_t)l*DI + t];
  __syncthreads();
  int o  = (t < DM) ? t : (t - DM);
  int d0 = (t < DM) ? 0 : DM;
  float acc = 0.f;
  #pragma unroll 8
  for (int dd = 0; dd < DM; dd++){
    int d = d0 + dd;
    acc += ym[d] * owT[d*DM + o];
  }
  part[t] = acc;
  __syncthreads();
  if (t < DM) out[l*DM + t] = part[t] + part[DM + t];
}

extern "C" void kernel_launch(void* const* d_in, const int* in_sizes, int n_in,
                              void* d_out, int out_size, void* d_ws, size_t ws_size,
                              hipStream_t stream){
  const float* x   = (const float*)d_in[0];
  const float* ipw = (const float*)d_in[1];
  const float* cw  = (const float*)d_in[2];
  const float* cb  = (const float*)d_in[3];
  const float* pw  = (const float*)d_in[4];
  const float* dtw = (const float*)d_in[5];
  const float* dtb = (const float*)d_in[6];
  const float* alg = (const float*)d_in[7];
  const float* Dsv = (const float*)d_in[8];
  const float* lng = (const float*)d_in[9];
  const float* lnb = (const float*)d_in[10];
  const float* ow  = (const float*)d_in[11];
  float* out = (float*)d_out;

  float* ws    = (float*)d_ws;
  float* x_    = ws; ws += L*DI;
  float* sz    = ws; ws += L*DI;
  float* xc    = ws; ws += L*DI;
  float* xdbp  = ws; ws += (size_t)KD*L*NCP;
  float* Pb    = ws; ws += (size_t)KD*NCH1*DI*DSTATE;
  float* Gb    = ws; ws += (size_t)KD*NCH1*DI*DSTATE;
  float* Hin   = ws; ws += (size_t)KD*NCH1*DI*DSTATE;
  float* oyT   = ws; ws += (size_t)L*KD*DI;
  float* ipwT  = ws; ws += 384*DM;
  float* pwT   = ws; ws += KD*DI*NCP;
  float* owT   = ws; ws += DM*DI;

  int prep_tot = 384*DM + KD*NC*DI + DM*DI + KD*DI*2;
  k_prep<<<(prep_tot + 255)/256, 256, 0, stream>>>(ipw, pw, ow, ipwT, pwT, owT);
  k_inproj<<<L/TL, 384, 0, stream>>>(x, ipwT, x_, sz);
  k_conv<<<(L*DI + 383)/384, 384, 0, stream>>>(x_, cw, cb, xc);
  k_xs1<<<KD*NCH1, 384, 0, stream>>>(xc, pwT, dtw, dtb, alg, xdbp, Pb, Gb);
  k_scan2<<<KD*DI, NCH1, 0, stream>>>(Pb, Gb, Hin);
  k_scan3<<<KD*NCH3, 384, 0, stream>>>(xdbp, xc, dtw, dtb, alg, Dsv, Hin, oyT);
  k_final<<<L, DI, 0, stream>>>(oyT, sz, lng, lnb, owT, out);
}

// Round 11
// 209.776 us; speedup vs baseline: 1.0590x; 1.0590x over previous
//
#include <hip/hip_runtime.h>

#define L 4096
#define HH 64
#define WW 64
#define DM 96
#define DI 192
#define DSTATE 16
#define DTR 6
#define NC 38   // DTR + 2*DSTATE
#define NCP 40  // padded x_dbl / pwT row stride (16B-aligned float4 groups)
#define KD 4
#define CHUNK 32
#define NCHUNK 128  // L / CHUNK
#define NS 8        // states per thread (DSTATE/2)
#define TL 8        // l-tile for in_proj
#define LOG2E 1.44269504f
#define LN2   0.69314718f

__device__ __forceinline__ float silu_f(float v){ return v / (1.f + __expf(-v)); }
__device__ __forceinline__ float softplus_f(float v){
  float a = fabsf(v);
  float e = exp2f(-a * LOG2E);
  return fmaxf(v, 0.f) + LN2 * log2f(1.f + e);
}

// ---------------- Kernel 0: weight transposes (+ pwT pad zero) ----------------
__global__ void k_prep(const float* __restrict__ ipw, const float* __restrict__ pw,
                       const float* __restrict__ ow,
                       float* __restrict__ ipwT, float* __restrict__ pwT,
                       float* __restrict__ owT){
  int i = blockIdx.x * 256 + threadIdx.x;
  if (i < 384*DM){ int o = i / DM, c = i % DM; ipwT[c*384 + o] = ipw[i]; }
  int j = i - 384*DM;
  if (j >= 0 && j < KD*NC*DI){
    int k = j / (NC*DI); int r = j % (NC*DI); int c = r / DI, d = r % DI;
    pwT[(k*DI + d)*NCP + c] = pw[j];          // padded stride 40
  }
  int m = i - 384*DM - KD*NC*DI;
  if (m >= 0 && m < DM*DI){ int o = m / DI, d = m % DI; owT[d*DM + o] = ow[m]; }
  int p = m - DM*DI;
  if (p >= 0 && p < KD*DI*2){                 // zero pad columns 38,39
    int kd = p >> 1, q = p & 1;
    pwT[kd*NCP + NC + q] = 0.f;
  }
}

// ---------------- Kernel 1: in_proj -> x_ , silu(z) ----------------
__global__ void k_inproj(const float* __restrict__ x, const float* __restrict__ wT,
                         float* __restrict__ xo, float* __restrict__ sz){
  int l0 = blockIdx.x * TL;          // grid = 512
  int t  = threadIdx.x;              // 384 threads
  __shared__ float xl[TL][DM];
  for (int j = t; j < TL*DM; j += 384) xl[j / DM][j % DM] = x[l0*DM + j];
  __syncthreads();
  float acc[TL];
  #pragma unroll
  for (int i = 0; i < TL; i++) acc[i] = 0.f;
  #pragma unroll 4
  for (int c = 0; c < DM; c++){
    float wv = wT[c*384 + t];
    #pragma unroll
    for (int i = 0; i < TL; i++) acc[i] += xl[i][c] * wv;
  }
  if (t < DI){
    #pragma unroll
    for (int i = 0; i < TL; i++) xo[(l0 + i)*DI + t] = acc[i];
  } else {
    int z = t - DI;
    #pragma unroll
    for (int i = 0; i < TL; i++) sz[(l0 + i)*DI + z] = silu_f(acc[i]);
  }
}

// -------- Kernel 2: depthwise 3x3 conv + bias + silu -> xcR (row) + xcC (transposed) ----
__global__ void k_conv(const float* __restrict__ xi, const float* __restrict__ cw,
                       const float* __restrict__ cb,
                       float* __restrict__ xcR, float* __restrict__ xcC){
  int idx = blockIdx.x * blockDim.x + threadIdx.x;
  if (idx >= L*DI) return;
  int d = idx % DI, l = idx / DI;
  int h = l >> 6, w = l & 63;
  float acc = cb[d];
  #pragma unroll
  for (int dy = 0; dy < 3; dy++){
    int hh = h + dy - 1;
    if (hh < 0 || hh >= HH) continue;
    #pragma unroll
    for (int dx = 0; dx < 3; dx++){
      int ww = w + dx - 1;
      if (ww < 0 || ww >= WW) continue;
      acc += xi[(hh*WW + ww)*DI + d] * cw[(dy*3 + dx)*DI + d];
    }
  }
  float v = silu_f(acc);
  xcR[idx] = v;
  int lT = ((l & 63) << 6) | (l >> 6);
  xcC[lT*DI + d] = v;        // coalesced in d
}

// ------- Kernel 3: FUSED x_dbl + scan pass 1 (per (k,chunk) block, 384 thr) -------
// xc staging is one CONTIGUOUS 24KB slab for every direction (xcR/xcC + reversal).
__global__ __launch_bounds__(384) void k_xs1(
    const float* __restrict__ xcR, const float* __restrict__ xcC,
    const float* __restrict__ pwT,
    const float* __restrict__ dtw, const float* __restrict__ dtb,
    const float* __restrict__ alogs,
    float* __restrict__ xdbp, float* __restrict__ Pb, float* __restrict__ Gb){
  int k  = blockIdx.x >> 7;   // grid = 4*128
  int ch = blockIdx.x & 127;
  int l0 = ch * CHUNK;
  int t  = threadIdx.x;
  __shared__ float sxc[CHUNK][DI + 1];   // pad: bank = (i + d) % 32
  __shared__ float sdt[CHUNK][8];
  __shared__ float sB[CHUNK][16];
  const float* buf = (k & 1) ? xcC : xcR;
  int base = (k & 2) ? (L - l0 - CHUNK) : l0;
  for (int j = t; j < CHUNK*DI; j += 384){
    int row = j / DI, dd = j % DI;
    int i = (k & 2) ? (CHUNK - 1 - row) : row;
    sxc[i][dd] = buf[(size_t)(base + row)*DI + dd];   // contiguous slab, coalesced
  }
  __syncthreads();
  // x_dbl tile: 32 rows x 40 cols; thread (i, cg): 4 outputs, full 192-dot
  if (t < 320){
    int i = t / 10, cg = t % 10;
    const float4* pr4 = (const float4*)(pwT + k*DI*NCP) + cg;
    float4 a = make_float4(0.f, 0.f, 0.f, 0.f);
    #pragma unroll 8
    for (int dd = 0; dd < DI; dd++){
      float v = sxc[i][dd];
      float4 w = pr4[dd*10];
      a.x += v*w.x; a.y += v*w.y; a.z += v*w.z; a.w += v*w.w;
    }
    *(float4*)&xdbp[(size_t)(k*L + l0 + i)*NCP + cg*4] = a;
    float av[4] = {a.x, a.y, a.z, a.w};
    int c0 = cg*4;
    #pragma unroll
    for (int q = 0; q < 4; q++){
      int c = c0 + q;
      if (c < DTR) sdt[i][c] = av[q];
      else if (c < DTR + DSTATE) sB[i][c - DTR] = av[q];
    }
  }
  int d = t >> 1, half = t & 1;
  float wr[DTR];
  #pragma unroll
  for (int r = 0; r < DTR; r++) wr[r] = dtw[(k*DI + d)*DTR + r];
  float bb = dtb[k*DI + d];
  float A2[NS];
  const float* ap = alogs + (k*DI + d)*DSTATE + half*NS;
  #pragma unroll
  for (int j = 0; j < NS; j++) A2[j] = -__expf(ap[j]) * LOG2E;
  float P[NS], G[NS];
  #pragma unroll
  for (int j = 0; j < NS; j++){ P[j] = 1.f; G[j] = 0.f; }
  __syncthreads();
  #pragma unroll 8
  for (int i = 0; i < CHUNK; i++){
    float xval = sxc[i][d];
    float dv = bb;
    #pragma unroll
    for (int r = 0; r < DTR; r++) dv += wr[r] * sdt[i][r];
    dv = softplus_f(dv);
    float tv = dv * xval;
    float4 b0 = *(const float4*)&sB[i][half*8];
    float4 b1 = *(const float4*)&sB[i][half*8 + 4];
    float Bv[NS] = {b0.x,b0.y,b0.z,b0.w,b1.x,b1.y,b1.z,b1.w};
    #pragma unroll
    for (int j = 0; j < NS; j++){
      float dA = exp2f(dv * A2[j]);
      G[j] = dA * G[j] + tv * Bv[j];
      P[j] *= dA;
    }
  }
  size_t bbase = (size_t)(k*NCHUNK + ch)*DI*DSTATE + t*NS;
  ((float4*)(Pb + bbase))[0] = make_float4(P[0],P[1],P[2],P[3]);
  ((float4*)(Pb + bbase))[1] = make_float4(P[4],P[5],P[6],P[7]);
  ((float4*)(Gb + bbase))[0] = make_float4(G[0],G[1],G[2],G[3]);
  ((float4*)(Gb + bbase))[1] = make_float4(G[4],G[5],G[6],G[7]);
}

// ---------------- Kernel 4: scan pass 2 — Hillis-Steele over 128 chunks ----------------
__global__ void k_scan2(const float* __restrict__ Pb, const float* __restrict__ Gb,
                        float* __restrict__ Hin){
  int k = blockIdx.x / DI;
  int d = blockIdx.x % DI;
  int c = threadIdx.x;   // chunk id, 128 threads
  float P[DSTATE], G[DSTATE];
  const float* Pp = Pb + ((size_t)(k*NCHUNK + c)*DI + d)*DSTATE;
  const float* Gp = Gb + ((size_t)(k*NCHUNK + c)*DI + d)*DSTATE;
  #pragma unroll
  for (int n = 0; n < DSTATE; n++){ P[n] = Pp[n]; G[n] = Gp[n]; }
  __shared__ float sP[NCHUNK][DSTATE + 1];
  __shared__ float sG[NCHUNK][DSTATE + 1];
  for (int off = 1; off < NCHUNK; off <<= 1){
    #pragma unroll
    for (int n = 0; n < DSTATE; n++){ sP[c][n] = P[n]; sG[c][n] = G[n]; }
    __syncthreads();
    if (c >= off){
      #pragma unroll
      for (int n = 0; n < DSTATE; n++){
        float a1 = sP[c - off][n], b1 = sG[c - off][n];
        G[n] = P[n]*b1 + G[n];
        P[n] = P[n]*a1;
      }
    }
    __syncthreads();
  }
  #pragma unroll
  for (int n = 0; n < DSTATE; n++) sG[c][n] = G[n];
  __syncthreads();
  float* Hp = Hin + ((size_t)(k*NCHUNK + c)*DI + d)*DSTATE;
  #pragma unroll
  for (int n = 0; n < DSTATE; n++) Hp[n] = (c == 0) ? 0.f : sG[c - 1][n];
}

// ---------------- Kernel 5: scan pass 3 — replay, emit oyT[l][k][d] ----------------
__global__ __launch_bounds__(384) void k_scan3(
    const float* __restrict__ xdbp,
    const float* __restrict__ xcR, const float* __restrict__ xcC,
    const float* __restrict__ dtw, const float* __restrict__ dtb,
    const float* __restrict__ alogs, const float* __restrict__ Dsv,
    const float* __restrict__ Hin, float* __restrict__ oyT){
  int k  = blockIdx.x >> 7;   // grid = 4*128
  int ch = blockIdx.x & 127;
  int l0 = ch * CHUNK;
  int t  = threadIdx.x;
  int d  = t >> 1, half = t & 1;
  __shared__ float sdt[CHUNK][8];
  __shared__ float sB[CHUNK][16];
  __shared__ float sC[CHUNK][16];
  __shared__ float sxc[CHUNK][DI + 1];
  for (int j = t; j < CHUNK*NCP; j += 384){
    int i = j / NCP, c = j % NCP;
    float v = xdbp[(size_t)(k*L + l0)*NCP + j];   // coalesced padded rows
    if (c < DTR) sdt[i][c] = v;
    else if (c < DTR + DSTATE) sB[i][c - DTR] = v;
    else if (c < NC) sC[i][c - DTR - DSTATE] = v;
  }
  const float* buf = (k & 1) ? xcC : xcR;
  int base = (k & 2) ? (L - l0 - CHUNK) : l0;
  for (int j = t; j < CHUNK*DI; j += 384){
    int row = j / DI, dd = j % DI;
    int i = (k & 2) ? (CHUNK - 1 - row) : row;
    sxc[i][dd] = buf[(size_t)(base + row)*DI + dd];
  }
  float wr[DTR];
  #pragma unroll
  for (int r = 0; r < DTR; r++) wr[r] = dtw[(k*DI + d)*DTR + r];
  float bb = dtb[k*DI + d];
  float A2[NS];
  const float* ap = alogs + (k*DI + d)*DSTATE + half*NS;
  #pragma unroll
  for (int j = 0; j < NS; j++) A2[j] = -__expf(ap[j]) * LOG2E;
  float h[NS];
  size_t hbase = (size_t)(k*NCHUNK + ch)*DI*DSTATE + t*NS;
  float4 h0 = ((const float4*)(Hin + hbase))[0];
  float4 h1 = ((const float4*)(Hin + hbase))[1];
  h[0]=h0.x; h[1]=h0.y; h[2]=h0.z; h[3]=h0.w;
  h[4]=h1.x; h[5]=h1.y; h[6]=h1.z; h[7]=h1.w;
  float Dv = Dsv[k*DI + d];
  __syncthreads();
  #pragma unroll 8
  for (int i = 0; i < CHUNK; i++){
    float xval = sxc[i][d];
    float dv = bb;
    #pragma unroll
    for (int r = 0; r < DTR; r++) dv += wr[r] * sdt[i][r];
    dv = softplus_f(dv);
    float tv = dv * xval;
    float4 b0 = *(const float4*)&sB[i][half*8];
    float4 b1 = *(const float4*)&sB[i][half*8 + 4];
    float4 c0 = *(const float4*)&sC[i][half*8];
    float4 c1 = *(const float4*)&sC[i][half*8 + 4];
    float Bv[NS] = {b0.x,b0.y,b0.z,b0.w,b1.x,b1.y,b1.z,b1.w};
    float Cv[NS] = {c0.x,c0.y,c0.z,c0.w,c1.x,c1.y,c1.z,c1.w};
    float y = (half == 0) ? Dv * xval : 0.f;
    #pragma unroll
    for (int j = 0; j < NS; j++){
      float dA = exp2f(dv * A2[j]);
      h[j] = dA * h[j] + tv * Bv[j];
      y += h[j] * Cv[j];
    }
    y += __shfl_xor(y, 1);
    if (half == 0) oyT[(size_t)(l0 + i)*KD*DI + k*DI + d] = y;
  }
}

// ---------------- Kernel 6: k-sum + LayerNorm + silu(z)*y + out proj ----------------
__global__ void k_final(const float* __restrict__ oyT, const float* __restrict__ sz,
                        const float* __restrict__ g, const float* __restrict__ b,
                        const float* __restrict__ owT, float* __restrict__ out){
  int l = blockIdx.x, t = threadIdx.x;  // 192 threads
  __shared__ float ym[DI];
  __shared__ float part[DI];
  __shared__ float red[6];
  float y = 0.f;
  #pragma unroll
  for (int k = 0; k < KD; k++) y += oyT[(size_t)l*KD*DI + k*DI + t];
  float s = y, s2 = y*y;
  #pragma unroll
  for (int off = 32; off; off >>= 1){ s += __shfl_down(s, off); s2 += __shfl_down(s2, off); }
  int wave = t >> 6, lane = t & 63;
  if (lane == 0){ red[wave] = s; red[3 + wave] = s2; }
  __syncthreads();
  float S  = red[0] + red[1] + red[2];
  float SQ = red[3] + red[4] + red[5];
  float mu  = S * (1.f/DI);
  float var = SQ * (1.f/DI) - mu*mu;
  float yn = (y - mu) * rsqrtf(var + 1e-5f) * g[t] + b[t];
  ym[t] = yn * sz[(size_t)l*DI + t];
  __syncthreads();
  int o  = (t < DM) ? t : (t - DM);
  int d0 = (t < DM) ? 0 : DM;
  float acc = 0.f;
  #pragma unroll 8
  for (int dd = 0; dd < DM; dd++){
    int d = d0 + dd;
    acc += ym[d] * owT[d*DM + o];
  }
  part[t] = acc;
  __syncthreads();
  if (t < DM) out[l*DM + t] = part[t] + part[DM + t];
}

extern "C" void kernel_launch(void* const* d_in, const int* in_sizes, int n_in,
                              void* d_out, int out_size, void* d_ws, size_t ws_size,
                              hipStream_t stream){
  const float* x   = (const float*)d_in[0];
  const float* ipw = (const float*)d_in[1];
  const float* cw  = (const float*)d_in[2];
  const float* cb  = (const float*)d_in[3];
  const float* pw  = (const float*)d_in[4];
  const float* dtw = (const float*)d_in[5];
  const float* dtb = (const float*)d_in[6];
  const float* alg = (const float*)d_in[7];
  const float* Dsv = (const float*)d_in[8];
  const float* lng = (const float*)d_in[9];
  const float* lnb = (const float*)d_in[10];
  const float* ow  = (const float*)d_in[11];
  float* out = (float*)d_out;

  float* ws    = (float*)d_ws;
  float* x_    = ws; ws += L*DI;
  float* sz    = ws; ws += L*DI;
  float* xcR   = ws; ws += L*DI;
  float* xcC   = ws; ws += L*DI;
  float* xdbp  = ws; ws += (size_t)KD*L*NCP;
  float* Pb    = ws; ws += (size_t)KD*NCHUNK*DI*DSTATE;
  float* Gb    = ws; ws += (size_t)KD*NCHUNK*DI*DSTATE;
  float* Hin   = ws; ws += (size_t)KD*NCHUNK*DI*DSTATE;
  float* oyT   = ws; ws += (size_t)L*KD*DI;
  float* ipwT  = ws; ws += 384*DM;
  float* pwT   = ws; ws += KD*DI*NCP;
  float* owT   = ws; ws += DM*DI;

  int prep_tot = 384*DM + KD*NC*DI + DM*DI + KD*DI*2;
  k_prep<<<(prep_tot + 255)/256, 256, 0, stream>>>(ipw, pw, ow, ipwT, pwT, owT);
  k_inproj<<<L/TL, 384, 0, stream>>>(x, ipwT, x_, sz);
  k_conv<<<(L*DI + 383)/384, 384, 0, stream>>>(x_, cw, cb, xcR, xcC);
  k_xs1<<<KD*NCHUNK, 384, 0, stream>>>(xcR, xcC, pwT, dtw, dtb, alg, xdbp, Pb, Gb);
  k_scan2<<<KD*DI, NCHUNK, 0, stream>>>(Pb, Gb, Hin);
  k_scan3<<<KD*NCHUNK, 384, 0, stream>>>(xdbp, xcR, xcC, dtw, dtb, alg, Dsv, Hin, oyT);
  k_final<<<L, DI, 0, stream>>>(oyT, sz, lng, lnb, owT, out);
}

// Round 12
// 199.517 us; speedup vs baseline: 1.1134x; 1.0514x over previous
//
#include <hip/hip_runtime.h>

#define L 4096
#define HH 64
#define WW 64
#define DM 96
#define DI 192
#define DSTATE 16
#define DTR 6
#define NC 38   // DTR + 2*DSTATE
#define NCP 40  // padded x_dbl / pwT row stride (16B-aligned float4 groups)
#define KD 4
#define CHUNK 32
#define NCHUNK 128  // L / CHUNK
#define NS 8        // states per thread (DSTATE/2)
#define TL 8        // l-tile for in_proj
#define LOG2E 1.44269504f
#define LN2   0.69314718f

__device__ __forceinline__ float silu_f(float v){ return v / (1.f + __expf(-v)); }
__device__ __forceinline__ float softplus_f(float v){
  float a = fabsf(v);
  float e = exp2f(-a * LOG2E);
  return fmaxf(v, 0.f) + LN2 * log2f(1.f + e);
}

// ---------------- Kernel 0: weight transposes (+ pwT pad zero) ----------------
__global__ void k_prep(const float* __restrict__ ipw, const float* __restrict__ pw,
                       const float* __restrict__ ow,
                       float* __restrict__ ipwT, float* __restrict__ pwT,
                       float* __restrict__ owT){
  int i = blockIdx.x * 256 + threadIdx.x;
  if (i < 384*DM){ int o = i / DM, c = i % DM; ipwT[c*384 + o] = ipw[i]; }
  int j = i - 384*DM;
  if (j >= 0 && j < KD*NC*DI){
    int k = j / (NC*DI); int r = j % (NC*DI); int c = r / DI, d = r % DI;
    pwT[(k*DI + d)*NCP + c] = pw[j];          // padded stride 40
  }
  int m = i - 384*DM - KD*NC*DI;
  if (m >= 0 && m < DM*DI){ int o = m / DI, d = m % DI; owT[d*DM + o] = ow[m]; }
  int p = m - DM*DI;
  if (p >= 0 && p < KD*DI*2){                 // zero pad columns 38,39
    int kd = p >> 1, q = p & 1;
    pwT[kd*NCP + NC + q] = 0.f;
  }
}

// ---------------- Kernel 1: in_proj -> x_ , silu(z) ----------------
__global__ void k_inproj(const float* __restrict__ x, const float* __restrict__ wT,
                         float* __restrict__ xo, float* __restrict__ sz){
  int l0 = blockIdx.x * TL;          // grid = 512
  int t  = threadIdx.x;              // 384 threads
  __shared__ float xl[TL][DM];
  for (int j = t; j < TL*DM; j += 384) xl[j / DM][j % DM] = x[l0*DM + j];
  __syncthreads();
  float acc[TL];
  #pragma unroll
  for (int i = 0; i < TL; i++) acc[i] = 0.f;
  #pragma unroll 4
  for (int c = 0; c < DM; c++){
    float wv = wT[c*384 + t];
    #pragma unroll
    for (int i = 0; i < TL; i++) acc[i] += xl[i][c] * wv;
  }
  if (t < DI){
    #pragma unroll
    for (int i = 0; i < TL; i++) xo[(l0 + i)*DI + t] = acc[i];
  } else {
    int z = t - DI;
    #pragma unroll
    for (int i = 0; i < TL; i++) sz[(l0 + i)*DI + z] = silu_f(acc[i]);
  }
}

// -------- Kernel 2: depthwise 3x3 conv + bias + silu -> xcR (row) + xcC (transposed) ----
__global__ void k_conv(const float* __restrict__ xi, const float* __restrict__ cw,
                       const float* __restrict__ cb,
                       float* __restrict__ xcR, float* __restrict__ xcC){
  int idx = blockIdx.x * blockDim.x + threadIdx.x;
  if (idx >= L*DI) return;
  int d = idx % DI, l = idx / DI;
  int h = l >> 6, w = l & 63;
  float acc = cb[d];
  #pragma unroll
  for (int dy = 0; dy < 3; dy++){
    int hh = h + dy - 1;
    if (hh < 0 || hh >= HH) continue;
    #pragma unroll
    for (int dx = 0; dx < 3; dx++){
      int ww = w + dx - 1;
      if (ww < 0 || ww >= WW) continue;
      acc += xi[(hh*WW + ww)*DI + d] * cw[(dy*3 + dx)*DI + d];
    }
  }
  float v = silu_f(acc);
  xcR[idx] = v;
  int lT = ((l & 63) << 6) | (l >> 6);
  xcC[lT*DI + d] = v;        // coalesced in d
}

// ------- Kernel 3: FUSED x_dbl + scan pass 1 (per (k,chunk) block, 384 thr) -------
// Weights for this k staged in LDS: matvec loop is pure LDS+VALU (no VMEM latency).
__global__ __launch_bounds__(384) void k_xs1(
    const float* __restrict__ xcR, const float* __restrict__ xcC,
    const float* __restrict__ pwT,
    const float* __restrict__ dtw, const float* __restrict__ dtb,
    const float* __restrict__ alogs,
    float* __restrict__ xdbp, float* __restrict__ Pb, float* __restrict__ Gb){
  int k  = blockIdx.x >> 7;   // grid = 4*128
  int ch = blockIdx.x & 127;
  int l0 = ch * CHUNK;
  int t  = threadIdx.x;
  __shared__ float swt[DI*NCP];          // 30.7 KB: this k's weight matrix
  __shared__ float sxc[CHUNK][DI + 1];   // 24.7 KB, pad: bank = (i + d) % 32
  __shared__ float sdt[CHUNK][8];
  __shared__ float sB[CHUNK][16];
  {  // stage weights, coalesced float4: 1920 float4 = 384 thr x 5
    const float4* src = (const float4*)(pwT + k*DI*NCP);
    float4* dst = (float4*)swt;
    #pragma unroll
    for (int q = 0; q < 5; q++) dst[t + q*384] = src[t + q*384];
  }
  const float* buf = (k & 1) ? xcC : xcR;
  int base = (k & 2) ? (L - l0 - CHUNK) : l0;
  for (int j = t; j < CHUNK*DI; j += 384){
    int row = j / DI, dd = j % DI;
    int i = (k & 2) ? (CHUNK - 1 - row) : row;
    sxc[i][dd] = buf[(size_t)(base + row)*DI + dd];   // contiguous slab, coalesced
  }
  __syncthreads();
  // x_dbl tile: 32 rows x 40 cols; thread (i, cg): 4 outputs, full 192-dot, LDS-only loop
  if (t < 320){
    int i = t / 10, cg = t % 10;
    float4 a = make_float4(0.f, 0.f, 0.f, 0.f);
    #pragma unroll 8
    for (int dd = 0; dd < DI; dd++){
      float v = sxc[i][dd];
      float4 w = *(const float4*)&swt[dd*NCP + cg*4];   // <=2-way bank alias: free
      a.x += v*w.x; a.y += v*w.y; a.z += v*w.z; a.w += v*w.w;
    }
    *(float4*)&xdbp[(size_t)(k*L + l0 + i)*NCP + cg*4] = a;
    float av[4] = {a.x, a.y, a.z, a.w};
    int c0 = cg*4;
    #pragma unroll
    for (int q = 0; q < 4; q++){
      int c = c0 + q;
      if (c < DTR) sdt[i][c] = av[q];
      else if (c < DTR + DSTATE) sB[i][c - DTR] = av[q];
    }
  }
  int d = t >> 1, half = t & 1;
  float wr[DTR];
  #pragma unroll
  for (int r = 0; r < DTR; r++) wr[r] = dtw[(k*DI + d)*DTR + r];
  float bb = dtb[k*DI + d];
  float A2[NS];
  const float* ap = alogs + (k*DI + d)*DSTATE + half*NS;
  #pragma unroll
  for (int j = 0; j < NS; j++) A2[j] = -__expf(ap[j]) * LOG2E;
  float P[NS], G[NS];
  #pragma unroll
  for (int j = 0; j < NS; j++){ P[j] = 1.f; G[j] = 0.f; }
  __syncthreads();
  #pragma unroll 8
  for (int i = 0; i < CHUNK; i++){
    float xval = sxc[i][d];
    float dv = bb;
    #pragma unroll
    for (int r = 0; r < DTR; r++) dv += wr[r] * sdt[i][r];
    dv = softplus_f(dv);
    float tv = dv * xval;
    float4 b0 = *(const float4*)&sB[i][half*8];
    float4 b1 = *(const float4*)&sB[i][half*8 + 4];
    float Bv[NS] = {b0.x,b0.y,b0.z,b0.w,b1.x,b1.y,b1.z,b1.w};
    #pragma unroll
    for (int j = 0; j < NS; j++){
      float dA = exp2f(dv * A2[j]);
      G[j] = dA * G[j] + tv * Bv[j];
      P[j] *= dA;
    }
  }
  size_t bbase = (size_t)(k*NCHUNK + ch)*DI*DSTATE + t*NS;
  ((float4*)(Pb + bbase))[0] = make_float4(P[0],P[1],P[2],P[3]);
  ((float4*)(Pb + bbase))[1] = make_float4(P[4],P[5],P[6],P[7]);
  ((float4*)(Gb + bbase))[0] = make_float4(G[0],G[1],G[2],G[3]);
  ((float4*)(Gb + bbase))[1] = make_float4(G[4],G[5],G[6],G[7]);
}

// ---------------- Kernel 4: scan pass 2 — Hillis-Steele over 128 chunks ----------------
__global__ void k_scan2(const float* __restrict__ Pb, const float* __restrict__ Gb,
                        float* __restrict__ Hin){
  int k = blockIdx.x / DI;
  int d = blockIdx.x % DI;
  int c = threadIdx.x;   // chunk id, 128 threads
  float P[DSTATE], G[DSTATE];
  const float* Pp = Pb + ((size_t)(k*NCHUNK + c)*DI + d)*DSTATE;
  const float* Gp = Gb + ((size_t)(k*NCHUNK + c)*DI + d)*DSTATE;
  #pragma unroll
  for (int n = 0; n < DSTATE; n++){ P[n] = Pp[n]; G[n] = Gp[n]; }
  __shared__ float sP[NCHUNK][DSTATE + 1];
  __shared__ float sG[NCHUNK][DSTATE + 1];
  for (int off = 1; off < NCHUNK; off <<= 1){
    #pragma unroll
    for (int n = 0; n < DSTATE; n++){ sP[c][n] = P[n]; sG[c][n] = G[n]; }
    __syncthreads();
    if (c >= off){
      #pragma unroll
      for (int n = 0; n < DSTATE; n++){
        float a1 = sP[c - off][n], b1 = sG[c - off][n];
        G[n] = P[n]*b1 + G[n];
        P[n] = P[n]*a1;
      }
    }
    __syncthreads();
  }
  #pragma unroll
  for (int n = 0; n < DSTATE; n++) sG[c][n] = G[n];
  __syncthreads();
  float* Hp = Hin + ((size_t)(k*NCHUNK + c)*DI + d)*DSTATE;
  #pragma unroll
  for (int n = 0; n < DSTATE; n++) Hp[n] = (c == 0) ? 0.f : sG[c - 1][n];
}

// ---------------- Kernel 5: scan pass 3 — replay, emit oyT[l][k][d] ----------------
__global__ __launch_bounds__(384) void k_scan3(
    const float* __restrict__ xdbp,
    const float* __restrict__ xcR, const float* __restrict__ xcC,
    const float* __restrict__ dtw, const float* __restrict__ dtb,
    const float* __restrict__ alogs, const float* __restrict__ Dsv,
    const float* __restrict__ Hin, float* __restrict__ oyT){
  int k  = blockIdx.x >> 7;   // grid = 4*128
  int ch = blockIdx.x & 127;
  int l0 = ch * CHUNK;
  int t  = threadIdx.x;
  int d  = t >> 1, half = t & 1;
  __shared__ float sdt[CHUNK][8];
  __shared__ float sB[CHUNK][16];
  __shared__ float sC[CHUNK][16];
  __shared__ float sxc[CHUNK][DI + 1];
  for (int j = t; j < CHUNK*NCP; j += 384){
    int i = j / NCP, c = j % NCP;
    float v = xdbp[(size_t)(k*L + l0)*NCP + j];   // coalesced padded rows
    if (c < DTR) sdt[i][c] = v;
    else if (c < DTR + DSTATE) sB[i][c - DTR] = v;
    else if (c < NC) sC[i][c - DTR - DSTATE] = v;
  }
  const float* buf = (k & 1) ? xcC : xcR;
  int base = (k & 2) ? (L - l0 - CHUNK) : l0;
  for (int j = t; j < CHUNK*DI; j += 384){
    int row = j / DI, dd = j % DI;
    int i = (k & 2) ? (CHUNK - 1 - row) : row;
    sxc[i][dd] = buf[(size_t)(base + row)*DI + dd];
  }
  float wr[DTR];
  #pragma unroll
  for (int r = 0; r < DTR; r++) wr[r] = dtw[(k*DI + d)*DTR + r];
  float bb = dtb[k*DI + d];
  float A2[NS];
  const float* ap = alogs + (k*DI + d)*DSTATE + half*NS;
  #pragma unroll
  for (int j = 0; j < NS; j++) A2[j] = -__expf(ap[j]) * LOG2E;
  float h[NS];
  size_t hbase = (size_t)(k*NCHUNK + ch)*DI*DSTATE + t*NS;
  float4 h0 = ((const float4*)(Hin + hbase))[0];
  float4 h1 = ((const float4*)(Hin + hbase))[1];
  h[0]=h0.x; h[1]=h0.y; h[2]=h0.z; h[3]=h0.w;
  h[4]=h1.x; h[5]=h1.y; h[6]=h1.z; h[7]=h1.w;
  float Dv = Dsv[k*DI + d];
  __syncthreads();
  #pragma unroll 8
  for (int i = 0; i < CHUNK; i++){
    float xval = sxc[i][d];
    float dv = bb;
    #pragma unroll
    for (int r = 0; r < DTR; r++) dv += wr[r] * sdt[i][r];
    dv = softplus_f(dv);
    float tv = dv * xval;
    float4 b0 = *(const float4*)&sB[i][half*8];
    float4 b1 = *(const float4*)&sB[i][half*8 + 4];
    float4 c0 = *(const float4*)&sC[i][half*8];
    float4 c1 = *(const float4*)&sC[i][half*8 + 4];
    float Bv[NS] = {b0.x,b0.y,b0.z,b0.w,b1.x,b1.y,b1.z,b1.w};
    float Cv[NS] = {c0.x,c0.y,c0.z,c0.w,c1.x,c1.y,c1.z,c1.w};
    float y = (half == 0) ? Dv * xval : 0.f;
    #pragma unroll
    for (int j = 0; j < NS; j++){
      float dA = exp2f(dv * A2[j]);
      h[j] = dA * h[j] + tv * Bv[j];
      y += h[j] * Cv[j];
    }
    y += __shfl_xor(y, 1);
    if (half == 0) oyT[(size_t)(l0 + i)*KD*DI + k*DI + d] = y;
  }
}

// ---------------- Kernel 6: k-sum + LayerNorm + silu(z)*y + out proj ----------------
__global__ void k_final(const float* __restrict__ oyT, const float* __restrict__ sz,
                        const float* __restrict__ g, const float* __restrict__ b,
                        const float* __restrict__ owT, float* __restrict__ out){
  int l = blockIdx.x, t = threadIdx.x;  // 192 threads
  __shared__ float ym[DI];
  __shared__ float part[DI];
  __shared__ float red[6];
  float y = 0.f;
  #pragma unroll
  for (int k = 0; k < KD; k++) y += oyT[(size_t)l*KD*DI + k*DI + t];
  float s = y, s2 = y*y;
  #pragma unroll
  for (int off = 32; off; off >>= 1){ s += __shfl_down(s, off); s2 += __shfl_down(s2, off); }
  int wave = t >> 6, lane = t & 63;
  if (lane == 0){ red[wave] = s; red[3 + wave] = s2; }
  __syncthreads();
  float S  = red[0] + red[1] + red[2];
  float SQ = red[3] + red[4] + red[5];
  float mu  = S * (1.f/DI);
  float var = SQ * (1.f/DI) - mu*mu;
  float yn = (y - mu) * rsqrtf(var + 1e-5f) * g[t] + b[t];
  ym[t] = yn * sz[(size_t)l*DI + t];
  __syncthreads();
  int o  = (t < DM) ? t : (t - DM);
  int d0 = (t < DM) ? 0 : DM;
  float acc = 0.f;
  #pragma unroll 8
  for (int dd = 0; dd < DM; dd++){
    int d = d0 + dd;
    acc += ym[d] * owT[d*DM + o];
  }
  part[t] = acc;
  __syncthreads();
  if (t < DM) out[l*DM + t] = part[t] + part[DM + t];
}

extern "C" void kernel_launch(void* const* d_in, const int* in_sizes, int n_in,
                              void* d_out, int out_size, void* d_ws, size_t ws_size,
                              hipStream_t stream){
  const float* x   = (const float*)d_in[0];
  const float* ipw = (const float*)d_in[1];
  const float* cw  = (const float*)d_in[2];
  const float* cb  = (const float*)d_in[3];
  const float* pw  = (const float*)d_in[4];
  const float* dtw = (const float*)d_in[5];
  const float* dtb = (const float*)d_in[6];
  const float* alg = (const float*)d_in[7];
  const float* Dsv = (const float*)d_in[8];
  const float* lng = (const float*)d_in[9];
  const float* lnb = (const float*)d_in[10];
  const float* ow  = (const float*)d_in[11];
  float* out = (float*)d_out;

  float* ws    = (float*)d_ws;
  float* x_    = ws; ws += L*DI;
  float* sz    = ws; ws += L*DI;
  float* xcR   = ws; ws += L*DI;
  float* xcC   = ws; ws += L*DI;
  float* xdbp  = ws; ws += (size_t)KD*L*NCP;
  float* Pb    = ws; ws += (size_t)KD*NCHUNK*DI*DSTATE;
  float* Gb    = ws; ws += (size_t)KD*NCHUNK*DI*DSTATE;
  float* Hin   = ws; ws += (size_t)KD*NCHUNK*DI*DSTATE;
  float* oyT   = ws; ws += (size_t)L*KD*DI;
  float* ipwT  = ws; ws += 384*DM;
  float* pwT   = ws; ws += KD*DI*NCP;
  float* owT   = ws; ws += DM*DI;

  int prep_tot = 384*DM + KD*NC*DI + DM*DI + KD*DI*2;
  k_prep<<<(prep_tot + 255)/256, 256, 0, stream>>>(ipw, pw, ow, ipwT, pwT, owT);
  k_inproj<<<L/TL, 384, 0, stream>>>(x, ipwT, x_, sz);
  k_conv<<<(L*DI + 383)/384, 384, 0, stream>>>(x_, cw, cb, xcR, xcC);
  k_xs1<<<KD*NCHUNK, 384, 0, stream>>>(xcR, xcC, pwT, dtw, dtb, alg, xdbp, Pb, Gb);
  k_scan2<<<KD*DI, NCHUNK, 0, stream>>>(Pb, Gb, Hin);
  k_scan3<<<KD*NCHUNK, 384, 0, stream>>>(xdbp, xcR, xcC, dtw, dtb, alg, Dsv, Hin, oyT);
  k_final<<<L, DI, 0, stream>>>(oyT, sz, lng, lnb, owT, out);
}

// Round 13
// 193.958 us; speedup vs baseline: 1.1453x; 1.0287x over previous
//
#include <hip/hip_runtime.h>

#define L 4096
#define HH 64
#define WW 64
#define DM 96
#define DI 192
#define DSTATE 16
#define DTR 6
#define NC 38   // DTR + 2*DSTATE
#define NCP 40  // padded x_dbl row stride; layout: [B(16) | C(16) | dt(6) | pad(2)]
#define CB 0    // B offset in new layout
#define CC 16   // C offset
#define CT 32   // dt offset
#define KD 4
#define CHUNK 32
#define NCHUNK 128  // L / CHUNK
#define NS 8        // states per thread (DSTATE/2)
#define TL 8        // l-tile for in_proj
#define LOG2E 1.44269504f
#define LN2   0.69314718f

__device__ __forceinline__ float silu_f(float v){ return v / (1.f + __expf(-v)); }
__device__ __forceinline__ float softplus_f(float v){
  float a = fabsf(v);
  float e = exp2f(-a * LOG2E);
  return fmaxf(v, 0.f) + LN2 * log2f(1.f + e);
}

// ---------------- Kernel 0: weight transposes (+ layout remap + pad zero) ----------------
__global__ void k_prep(const float* __restrict__ ipw, const float* __restrict__ pw,
                       const float* __restrict__ ow,
                       float* __restrict__ ipwT, float* __restrict__ pwT,
                       float* __restrict__ owT){
  int i = blockIdx.x * 256 + threadIdx.x;
  if (i < 384*DM){ int o = i / DM, c = i % DM; ipwT[c*384 + o] = ipw[i]; }
  int j = i - 384*DM;
  if (j >= 0 && j < KD*NC*DI){
    int k = j / (NC*DI); int r = j % (NC*DI); int c = r / DI, d = r % DI;
    int nc = (c < DTR) ? (CT + c) : (c - DTR);   // dt->32.., B->0.., C->16..
    pwT[(k*DI + d)*NCP + nc] = pw[j];
  }
  int m = i - 384*DM - KD*NC*DI;
  if (m >= 0 && m < DM*DI){ int o = m / DI, d = m % DI; owT[d*DM + o] = ow[m]; }
  int p = m - DM*DI;
  if (p >= 0 && p < KD*DI*2){                 // zero pad columns 38,39
    int kd = p >> 1, q = p & 1;
    pwT[kd*NCP + NC + q] = 0.f;
  }
}

// ---------------- Kernel 1: in_proj -> x_ , silu(z) ----------------
__global__ void k_inproj(const float* __restrict__ x, const float* __restrict__ wT,
                         float* __restrict__ xo, float* __restrict__ sz){
  int l0 = blockIdx.x * TL;          // grid = 512
  int t  = threadIdx.x;              // 384 threads
  __shared__ float xl[TL][DM];
  for (int j = t; j < TL*DM; j += 384) xl[j / DM][j % DM] = x[l0*DM + j];
  __syncthreads();
  float acc[TL];
  #pragma unroll
  for (int i = 0; i < TL; i++) acc[i] = 0.f;
  #pragma unroll 4
  for (int c = 0; c < DM; c++){
    float wv = wT[c*384 + t];
    #pragma unroll
    for (int i = 0; i < TL; i++) acc[i] += xl[i][c] * wv;
  }
  if (t < DI){
    #pragma unroll
    for (int i = 0; i < TL; i++) xo[(l0 + i)*DI + t] = acc[i];
  } else {
    int z = t - DI;
    #pragma unroll
    for (int i = 0; i < TL; i++) sz[(l0 + i)*DI + z] = silu_f(acc[i]);
  }
}

// -------- Kernel 2: depthwise 3x3 conv + bias + silu -> xcR (row) + xcC (transposed) ----
__global__ void k_conv(const float* __restrict__ xi, const float* __restrict__ cw,
                       const float* __restrict__ cb,
                       float* __restrict__ xcR, float* __restrict__ xcC){
  int idx = blockIdx.x * blockDim.x + threadIdx.x;
  if (idx >= L*DI) return;
  int d = idx % DI, l = idx / DI;
  int h = l >> 6, w = l & 63;
  float acc = cb[d];
  #pragma unroll
  for (int dy = 0; dy < 3; dy++){
    int hh = h + dy - 1;
    if (hh < 0 || hh >= HH) continue;
    #pragma unroll
    for (int dx = 0; dx < 3; dx++){
      int ww = w + dx - 1;
      if (ww < 0 || ww >= WW) continue;
      acc += xi[(hh*WW + ww)*DI + d] * cw[(dy*3 + dx)*DI + d];
    }
  }
  float v = silu_f(acc);
  xcR[idx] = v;
  int lT = ((l & 63) << 6) | (l >> 6);
  xcC[lT*DI + d] = v;        // coalesced in d
}

// ------- Kernel 3: FUSED x_dbl + scan pass 1 (per (k,chunk) block, 384 thr) -------
// Weights in LDS (pure LDS+VALU matvec); unified aligned sxd tile in new layout.
__global__ __launch_bounds__(384) void k_xs1(
    const float* __restrict__ xcR, const float* __restrict__ xcC,
    const float* __restrict__ pwT,
    const float* __restrict__ dtw, const float* __restrict__ dtb,
    const float* __restrict__ alogs,
    float* __restrict__ xdbp, float* __restrict__ Pb, float* __restrict__ Gb){
  int k  = blockIdx.x >> 7;   // grid = 4*128
  int ch = blockIdx.x & 127;
  int l0 = ch * CHUNK;
  int t  = threadIdx.x;
  __shared__ float swt[DI*NCP];          // 30.7 KB: this k's weight matrix
  __shared__ float sxc[CHUNK][DI + 1];   // 24.7 KB
  __shared__ float sxd[CHUNK][NCP];      // 5.1 KB: x_dbl tile, [B|C|dt|pad]
  {  // stage weights, coalesced float4: 1920 float4 = 384 thr x 5
    const float4* src = (const float4*)(pwT + k*DI*NCP);
    float4* dst = (float4*)swt;
    #pragma unroll
    for (int q = 0; q < 5; q++) dst[t + q*384] = src[t + q*384];
  }
  const float* buf = (k & 1) ? xcC : xcR;
  int base = (k & 2) ? (L - l0 - CHUNK) : l0;
  for (int j = t; j < CHUNK*DI; j += 384){
    int row = j / DI, dd = j % DI;
    int i = (k & 2) ? (CHUNK - 1 - row) : row;
    sxc[i][dd] = buf[(size_t)(base + row)*DI + dd];   // contiguous slab, coalesced
  }
  __syncthreads();
  // x_dbl tile: 32 rows x 40 cols; thread (i, cg): aligned float4 out, LDS-only loop
  if (t < 320){
    int i = t / 10, cg = t % 10;
    float4 a = make_float4(0.f, 0.f, 0.f, 0.f);
    #pragma unroll 8
    for (int dd = 0; dd < DI; dd++){
      float v = sxc[i][dd];
      float4 w = *(const float4*)&swt[dd*NCP + cg*4];
      a.x += v*w.x; a.y += v*w.y; a.z += v*w.z; a.w += v*w.w;
    }
    *(float4*)&sxd[i][cg*4] = a;
    *(float4*)&xdbp[(size_t)(k*L + l0 + i)*NCP + cg*4] = a;
  }
  int d = t >> 1, half = t & 1;
  float wr[DTR];
  #pragma unroll
  for (int r = 0; r < DTR; r++) wr[r] = dtw[(k*DI + d)*DTR + r];
  float bb = dtb[k*DI + d];
  float A2[NS];
  const float* ap = alogs + (k*DI + d)*DSTATE + half*NS;
  #pragma unroll
  for (int j = 0; j < NS; j++) A2[j] = -__expf(ap[j]) * LOG2E;
  float P[NS], G[NS];
  #pragma unroll
  for (int j = 0; j < NS; j++){ P[j] = 1.f; G[j] = 0.f; }
  __syncthreads();
  #pragma unroll 8
  for (int i = 0; i < CHUNK; i++){
    float xval = sxc[i][d];
    float dv = bb;
    #pragma unroll
    for (int r = 0; r < DTR; r++) dv += wr[r] * sxd[i][CT + r];
    dv = softplus_f(dv);
    float tv = dv * xval;
    float4 b0 = *(const float4*)&sxd[i][CB + half*8];
    float4 b1 = *(const float4*)&sxd[i][CB + half*8 + 4];
    float Bv[NS] = {b0.x,b0.y,b0.z,b0.w,b1.x,b1.y,b1.z,b1.w};
    #pragma unroll
    for (int j = 0; j < NS; j++){
      float dA = exp2f(dv * A2[j]);
      G[j] = dA * G[j] + tv * Bv[j];
      P[j] *= dA;
    }
  }
  size_t bbase = (size_t)(k*NCHUNK + ch)*DI*DSTATE + t*NS;
  ((float4*)(Pb + bbase))[0] = make_float4(P[0],P[1],P[2],P[3]);
  ((float4*)(Pb + bbase))[1] = make_float4(P[4],P[5],P[6],P[7]);
  ((float4*)(Gb + bbase))[0] = make_float4(G[0],G[1],G[2],G[3]);
  ((float4*)(Gb + bbase))[1] = make_float4(G[4],G[5],G[6],G[7]);
}

// ---------------- Kernel 4: scan pass 2 — Hillis-Steele over 128 chunks ----------------
__global__ void k_scan2(const float* __restrict__ Pb, const float* __restrict__ Gb,
                        float* __restrict__ Hin){
  int k = blockIdx.x / DI;
  int d = blockIdx.x % DI;
  int c = threadIdx.x;   // chunk id, 128 threads
  float P[DSTATE], G[DSTATE];
  size_t ibase = ((size_t)(k*NCHUNK + c)*DI + d)*DSTATE;
  #pragma unroll
  for (int q = 0; q < 4; q++){
    float4 pv = ((const float4*)(Pb + ibase))[q];
    float4 gv = ((const float4*)(Gb + ibase))[q];
    P[q*4+0]=pv.x; P[q*4+1]=pv.y; P[q*4+2]=pv.z; P[q*4+3]=pv.w;
    G[q*4+0]=gv.x; G[q*4+1]=gv.y; G[q*4+2]=gv.z; G[q*4+3]=gv.w;
  }
  __shared__ float sP[NCHUNK][DSTATE + 1];
  __shared__ float sG[NCHUNK][DSTATE + 1];
  for (int off = 1; off < NCHUNK; off <<= 1){
    #pragma unroll
    for (int n = 0; n < DSTATE; n++){ sP[c][n] = P[n]; sG[c][n] = G[n]; }
    __syncthreads();
    if (c >= off){
      #pragma unroll
      for (int n = 0; n < DSTATE; n++){
        float a1 = sP[c - off][n], b1 = sG[c - off][n];
        G[n] = P[n]*b1 + G[n];
        P[n] = P[n]*a1;
      }
    }
    __syncthreads();
  }
  #pragma unroll
  for (int n = 0; n < DSTATE; n++) sG[c][n] = G[n];
  __syncthreads();
  float4* Hp = (float4*)(Hin + ibase);
  if (c == 0){
    float4 z = make_float4(0.f,0.f,0.f,0.f);
    #pragma unroll
    for (int q = 0; q < 4; q++) Hp[q] = z;
  } else {
    #pragma unroll
    for (int q = 0; q < 4; q++)
      Hp[q] = make_float4(sG[c-1][q*4], sG[c-1][q*4+1], sG[c-1][q*4+2], sG[c-1][q*4+3]);
  }
}

// ---------------- Kernel 5: scan pass 3 — replay, emit oyT[l][k][d] ----------------
__global__ __launch_bounds__(384) void k_scan3(
    const float* __restrict__ xdbp,
    const float* __restrict__ xcR, const float* __restrict__ xcC,
    const float* __restrict__ dtw, const float* __restrict__ dtb,
    const float* __restrict__ alogs, const float* __restrict__ Dsv,
    const float* __restrict__ Hin, float* __restrict__ oyT){
  int k  = blockIdx.x >> 7;   // grid = 4*128
  int ch = blockIdx.x & 127;
  int l0 = ch * CHUNK;
  int t  = threadIdx.x;
  int d  = t >> 1, half = t & 1;
  __shared__ float sxd[CHUNK][NCP];      // unified aligned tile, branch-free copy
  __shared__ float sxc[CHUNK][DI + 1];
  {
    const float4* src = (const float4*)(xdbp + (size_t)(k*L + l0)*NCP);
    float4* dst = (float4*)&sxd[0][0];
    for (int j = t; j < CHUNK*NCP/4; j += 384) dst[j] = src[j];
  }
  const float* buf = (k & 1) ? xcC : xcR;
  int base = (k & 2) ? (L - l0 - CHUNK) : l0;
  for (int j = t; j < CHUNK*DI; j += 384){
    int row = j / DI, dd = j % DI;
    int i = (k & 2) ? (CHUNK - 1 - row) : row;
    sxc[i][dd] = buf[(size_t)(base + row)*DI + dd];
  }
  float wr[DTR];
  #pragma unroll
  for (int r = 0; r < DTR; r++) wr[r] = dtw[(k*DI + d)*DTR + r];
  float bb = dtb[k*DI + d];
  float A2[NS];
  const float* ap = alogs + (k*DI + d)*DSTATE + half*NS;
  #pragma unroll
  for (int j = 0; j < NS; j++) A2[j] = -__expf(ap[j]) * LOG2E;
  float h[NS];
  size_t hbase = (size_t)(k*NCHUNK + ch)*DI*DSTATE + t*NS;
  float4 h0 = ((const float4*)(Hin + hbase))[0];
  float4 h1 = ((const float4*)(Hin + hbase))[1];
  h[0]=h0.x; h[1]=h0.y; h[2]=h0.z; h[3]=h0.w;
  h[4]=h1.x; h[5]=h1.y; h[6]=h1.z; h[7]=h1.w;
  float Dv = Dsv[k*DI + d];
  __syncthreads();
  #pragma unroll 8
  for (int i = 0; i < CHUNK; i++){
    float xval = sxc[i][d];
    float dv = bb;
    #pragma unroll
    for (int r = 0; r < DTR; r++) dv += wr[r] * sxd[i][CT + r];
    dv = softplus_f(dv);
    float tv = dv * xval;
    float4 b0 = *(const float4*)&sxd[i][CB + half*8];
    float4 b1 = *(const float4*)&sxd[i][CB + half*8 + 4];
    float4 c0 = *(const float4*)&sxd[i][CC + half*8];
    float4 c1 = *(const float4*)&sxd[i][CC + half*8 + 4];
    float Bv[NS] = {b0.x,b0.y,b0.z,b0.w,b1.x,b1.y,b1.z,b1.w};
    float Cv[NS] = {c0.x,c0.y,c0.z,c0.w,c1.x,c1.y,c1.z,c1.w};
    float y = (half == 0) ? Dv * xval : 0.f;
    #pragma unroll
    for (int j = 0; j < NS; j++){
      float dA = exp2f(dv * A2[j]);
      h[j] = dA * h[j] + tv * Bv[j];
      y += h[j] * Cv[j];
    }
    y += __shfl_xor(y, 1);
    if (half == 0) oyT[(size_t)(l0 + i)*KD*DI + k*DI + d] = y;
  }
}

// ---------------- Kernel 6: k-sum + LayerNorm + silu(z)*y + out proj ----------------
__global__ void k_final(const float* __restrict__ oyT, const float* __restrict__ sz,
                        const float* __restrict__ g, const float* __restrict__ b,
                        const float* __restrict__ owT, float* __restrict__ out){
  int l = blockIdx.x, t = threadIdx.x;  // 192 threads
  __shared__ float ym[DI];
  __shared__ float part[DI];
  __shared__ float red[6];
  float y = 0.f;
  #pragma unroll
  for (int k = 0; k < KD; k++) y += oyT[(size_t)l*KD*DI + k*DI + t];
  float s = y, s2 = y*y;
  #pragma unroll
  for (int off = 32; off; off >>= 1){ s += __shfl_down(s, off); s2 += __shfl_down(s2, off); }
  int wave = t >> 6, lane = t & 63;
  if (lane == 0){ red[wave] = s; red[3 + wave] = s2; }
  __syncthreads();
  float S  = red[0] + red[1] + red[2];
  float SQ = red[3] + red[4] + red[5];
  float mu  = S * (1.f/DI);
  float var = SQ * (1.f/DI) - mu*mu;
  float yn = (y - mu) * rsqrtf(var + 1e-5f) * g[t] + b[t];
  ym[t] = yn * sz[(size_t)l*DI + t];
  __syncthreads();
  int o  = (t < DM) ? t : (t - DM);
  int d0 = (t < DM) ? 0 : DM;
  float acc = 0.f;
  #pragma unroll 8
  for (int dd = 0; dd < DM; dd++){
    int d = d0 + dd;
    acc += ym[d] * owT[d*DM + o];
  }
  part[t] = acc;
  __syncthreads();
  if (t < DM) out[l*DM + t] = part[t] + part[DM + t];
}

extern "C" void kernel_launch(void* const* d_in, const int* in_sizes, int n_in,
                              void* d_out, int out_size, void* d_ws, size_t ws_size,
                              hipStream_t stream){
  const float* x   = (const float*)d_in[0];
  const float* ipw = (const float*)d_in[1];
  const float* cw  = (const float*)d_in[2];
  const float* cb  = (const float*)d_in[3];
  const float* pw  = (const float*)d_in[4];
  const float* dtw = (const float*)d_in[5];
  const float* dtb = (const float*)d_in[6];
  const float* alg = (const float*)d_in[7];
  const float* Dsv = (const float*)d_in[8];
  const float* lng = (const float*)d_in[9];
  const float* lnb = (const float*)d_in[10];
  const float* ow  = (const float*)d_in[11];
  float* out = (float*)d_out;

  float* ws    = (float*)d_ws;
  float* x_    = ws; ws += L*DI;
  float* sz    = ws; ws += L*DI;
  float* xcR   = ws; ws += L*DI;
  float* xcC   = ws; ws += L*DI;
  float* xdbp  = ws; ws += (size_t)KD*L*NCP;
  float* Pb    = ws; ws += (size_t)KD*NCHUNK*DI*DSTATE;
  float* Gb    = ws; ws += (size_t)KD*NCHUNK*DI*DSTATE;
  float* Hin   = ws; ws += (size_t)KD*NCHUNK*DI*DSTATE;
  float* oyT   = ws; ws += (size_t)L*KD*DI;
  float* ipwT  = ws; ws += 384*DM;
  float* pwT   = ws; ws += KD*DI*NCP;
  float* owT   = ws; ws += DM*DI;

  int prep_tot = 384*DM + KD*NC*DI + DM*DI + KD*DI*2;
  k_prep<<<(prep_tot + 255)/256, 256, 0, stream>>>(ipw, pw, ow, ipwT, pwT, owT);
  k_inproj<<<L/TL, 384, 0, stream>>>(x, ipwT, x_, sz);
  k_conv<<<(L*DI + 383)/384, 384, 0, stream>>>(x_, cw, cb, xcR, xcC);
  k_xs1<<<KD*NCHUNK, 384, 0, stream>>>(xcR, xcC, pwT, dtw, dtb, alg, xdbp, Pb, Gb);
  k_scan2<<<KD*DI, NCHUNK, 0, stream>>>(Pb, Gb, Hin);
  k_scan3<<<KD*NCHUNK, 384, 0, stream>>>(xdbp, xcR, xcC, dtw, dtb, alg, Dsv, Hin, oyT);
  k_final<<<L, DI, 0, stream>>>(oyT, sz, lng, lnb, owT, out);
}

// Round 14
// 193.476 us; speedup vs baseline: 1.1482x; 1.0025x over previous
//
#include <hip/hip_runtime.h>

#define L 4096
#define HH 64
#define WW 64
#define DM 96
#define DI 192
#define DSTATE 16
#define DTR 6
#define NC 38   // DTR + 2*DSTATE
#define NCP 40  // padded x_dbl row stride; layout: [B(16) | C(16) | dt(6) | pad(2)]
#define CB 0    // B offset in new layout
#define CC 16   // C offset
#define CT 32   // dt offset
#define KD 4
#define CHUNK 32
#define NCHUNK 128  // L / CHUNK
#define NS 8        // states per thread (DSTATE/2)
#define TL 8        // l-tile for in_proj
#define LOG2E 1.44269504f
#define LN2   0.69314718f

__device__ __forceinline__ float silu_f(float v){ return v / (1.f + __expf(-v)); }
__device__ __forceinline__ float softplus_f(float v){
  float a = fabsf(v);
  float e = exp2f(-a * LOG2E);
  return fmaxf(v, 0.f) + LN2 * log2f(1.f + e);
}

// ---------------- Kernel 0: weight transposes (+ layout remap + pad zero) ----------------
__global__ void k_prep(const float* __restrict__ ipw, const float* __restrict__ pw,
                       const float* __restrict__ ow,
                       float* __restrict__ ipwT, float* __restrict__ pwT,
                       float* __restrict__ owT){
  int i = blockIdx.x * 256 + threadIdx.x;
  if (i < 384*DM){ int o = i / DM, c = i % DM; ipwT[c*384 + o] = ipw[i]; }
  int j = i - 384*DM;
  if (j >= 0 && j < KD*NC*DI){
    int k = j / (NC*DI); int r = j % (NC*DI); int c = r / DI, d = r % DI;
    int nc = (c < DTR) ? (CT + c) : (c - DTR);   // dt->32.., B->0.., C->16..
    pwT[(k*DI + d)*NCP + nc] = pw[j];
  }
  int m = i - 384*DM - KD*NC*DI;
  if (m >= 0 && m < DM*DI){ int o = m / DI, d = m % DI; owT[d*DM + o] = ow[m]; }
  int p = m - DM*DI;
  if (p >= 0 && p < KD*DI*2){                 // zero pad columns 38,39
    int kd = p >> 1, q = p & 1;
    pwT[kd*NCP + NC + q] = 0.f;
  }
}

// ---------------- Kernel 1: in_proj -> x_ , silu(z) ----------------
__global__ void k_inproj(const float* __restrict__ x, const float* __restrict__ wT,
                         float* __restrict__ xo, float* __restrict__ sz){
  int l0 = blockIdx.x * TL;          // grid = 512
  int t  = threadIdx.x;              // 384 threads
  __shared__ float xl[TL][DM];
  for (int j = t; j < TL*DM; j += 384) xl[j / DM][j % DM] = x[l0*DM + j];
  __syncthreads();
  float acc[TL];
  #pragma unroll
  for (int i = 0; i < TL; i++) acc[i] = 0.f;
  #pragma unroll 4
  for (int c = 0; c < DM; c++){
    float wv = wT[c*384 + t];
    #pragma unroll
    for (int i = 0; i < TL; i++) acc[i] += xl[i][c] * wv;
  }
  if (t < DI){
    #pragma unroll
    for (int i = 0; i < TL; i++) xo[(l0 + i)*DI + t] = acc[i];
  } else {
    int z = t - DI;
    #pragma unroll
    for (int i = 0; i < TL; i++) sz[(l0 + i)*DI + z] = silu_f(acc[i]);
  }
}

// -------- Kernel 2: depthwise 3x3 conv + bias + silu -> xcR (row) + xcC (transposed) ----
__global__ void k_conv(const float* __restrict__ xi, const float* __restrict__ cw,
                       const float* __restrict__ cb,
                       float* __restrict__ xcR, float* __restrict__ xcC){
  int idx = blockIdx.x * blockDim.x + threadIdx.x;
  if (idx >= L*DI) return;
  int d = idx % DI, l = idx / DI;
  int h = l >> 6, w = l & 63;
  float acc = cb[d];
  #pragma unroll
  for (int dy = 0; dy < 3; dy++){
    int hh = h + dy - 1;
    if (hh < 0 || hh >= HH) continue;
    #pragma unroll
    for (int dx = 0; dx < 3; dx++){
      int ww = w + dx - 1;
      if (ww < 0 || ww >= WW) continue;
      acc += xi[(hh*WW + ww)*DI + d] * cw[(dy*3 + dx)*DI + d];
    }
  }
  float v = silu_f(acc);
  xcR[idx] = v;
  int lT = ((l & 63) << 6) | (l >> 6);
  xcC[lT*DI + d] = v;        // coalesced in d
}

// ------- Kernel 3: FUSED x_dbl + scan pass 1 (per (k,chunk) block, 384 thr) -------
// Weights in LDS; matvec does 2 rows/thread so each weight b128 read feeds 8 MACs.
__global__ __launch_bounds__(384) void k_xs1(
    const float* __restrict__ xcR, const float* __restrict__ xcC,
    const float* __restrict__ pwT,
    const float* __restrict__ dtw, const float* __restrict__ dtb,
    const float* __restrict__ alogs,
    float* __restrict__ xdbp, float* __restrict__ Pb, float* __restrict__ Gb){
  int k  = blockIdx.x >> 7;   // grid = 4*128
  int ch = blockIdx.x & 127;
  int l0 = ch * CHUNK;
  int t  = threadIdx.x;
  __shared__ float swt[DI*NCP];          // 30.7 KB: this k's weight matrix
  __shared__ float sxc[CHUNK][DI + 1];   // 24.7 KB
  __shared__ float sxd[CHUNK][NCP];      // 5.1 KB: x_dbl tile, [B|C|dt|pad]
  {  // stage weights, coalesced float4: 1920 float4 = 384 thr x 5
    const float4* src = (const float4*)(pwT + k*DI*NCP);
    float4* dst = (float4*)swt;
    #pragma unroll
    for (int q = 0; q < 5; q++) dst[t + q*384] = src[t + q*384];
  }
  const float* buf = (k & 1) ? xcC : xcR;
  int base = (k & 2) ? (L - l0 - CHUNK) : l0;
  for (int j = t; j < CHUNK*DI; j += 384){
    int row = j / DI, dd = j % DI;
    int i = (k & 2) ? (CHUNK - 1 - row) : row;
    sxc[i][dd] = buf[(size_t)(base + row)*DI + dd];   // contiguous slab, coalesced
  }
  __syncthreads();
  // x_dbl tile: thread (p, cg) computes rows 2p,2p+1 x cols [cg*4,cg*4+4): shared w-read
  if (t < 160){
    int p = t / 10, cg = t % 10;
    int i0 = 2*p, i1 = 2*p + 1;
    float4 a0 = make_float4(0.f,0.f,0.f,0.f);
    float4 a1 = make_float4(0.f,0.f,0.f,0.f);
    #pragma unroll 8
    for (int dd = 0; dd < DI; dd++){
      float4 w = *(const float4*)&swt[dd*NCP + cg*4];
      float v0 = sxc[i0][dd];
      float v1 = sxc[i1][dd];
      a0.x += v0*w.x; a0.y += v0*w.y; a0.z += v0*w.z; a0.w += v0*w.w;
      a1.x += v1*w.x; a1.y += v1*w.y; a1.z += v1*w.z; a1.w += v1*w.w;
    }
    *(float4*)&sxd[i0][cg*4] = a0;
    *(float4*)&sxd[i1][cg*4] = a1;
    *(float4*)&xdbp[(size_t)(k*L + l0 + i0)*NCP + cg*4] = a0;
    *(float4*)&xdbp[(size_t)(k*L + l0 + i1)*NCP + cg*4] = a1;
  }
  int d = t >> 1, half = t & 1;
  float wr[DTR];
  #pragma unroll
  for (int r = 0; r < DTR; r++) wr[r] = dtw[(k*DI + d)*DTR + r];
  float bb = dtb[k*DI + d];
  float A2[NS];
  const float* ap = alogs + (k*DI + d)*DSTATE + half*NS;
  #pragma unroll
  for (int j = 0; j < NS; j++) A2[j] = -__expf(ap[j]) * LOG2E;
  float P[NS], G[NS];
  #pragma unroll
  for (int j = 0; j < NS; j++){ P[j] = 1.f; G[j] = 0.f; }
  __syncthreads();
  #pragma unroll 8
  for (int i = 0; i < CHUNK; i++){
    float xval = sxc[i][d];
    float dv = bb;
    #pragma unroll
    for (int r = 0; r < DTR; r++) dv += wr[r] * sxd[i][CT + r];
    dv = softplus_f(dv);
    float tv = dv * xval;
    float4 b0 = *(const float4*)&sxd[i][CB + half*8];
    float4 b1 = *(const float4*)&sxd[i][CB + half*8 + 4];
    float Bv[NS] = {b0.x,b0.y,b0.z,b0.w,b1.x,b1.y,b1.z,b1.w};
    #pragma unroll
    for (int j = 0; j < NS; j++){
      float dA = exp2f(dv * A2[j]);
      G[j] = dA * G[j] + tv * Bv[j];
      P[j] *= dA;
    }
  }
  size_t bbase = (size_t)(k*NCHUNK + ch)*DI*DSTATE + t*NS;
  ((float4*)(Pb + bbase))[0] = make_float4(P[0],P[1],P[2],P[3]);
  ((float4*)(Pb + bbase))[1] = make_float4(P[4],P[5],P[6],P[7]);
  ((float4*)(Gb + bbase))[0] = make_float4(G[0],G[1],G[2],G[3]);
  ((float4*)(Gb + bbase))[1] = make_float4(G[4],G[5],G[6],G[7]);
}

// ---------------- Kernel 4: scan pass 2 — Hillis-Steele over 128 chunks ----------------
__global__ void k_scan2(const float* __restrict__ Pb, const float* __restrict__ Gb,
                        float* __restrict__ Hin){
  int k = blockIdx.x / DI;
  int d = blockIdx.x % DI;
  int c = threadIdx.x;   // chunk id, 128 threads
  float P[DSTATE], G[DSTATE];
  size_t ibase = ((size_t)(k*NCHUNK + c)*DI + d)*DSTATE;
  #pragma unroll
  for (int q = 0; q < 4; q++){
    float4 pv = ((const float4*)(Pb + ibase))[q];
    float4 gv = ((const float4*)(Gb + ibase))[q];
    P[q*4+0]=pv.x; P[q*4+1]=pv.y; P[q*4+2]=pv.z; P[q*4+3]=pv.w;
    G[q*4+0]=gv.x; G[q*4+1]=gv.y; G[q*4+2]=gv.z; G[q*4+3]=gv.w;
  }
  __shared__ float sP[NCHUNK][DSTATE + 1];
  __shared__ float sG[NCHUNK][DSTATE + 1];
  for (int off = 1; off < NCHUNK; off <<= 1){
    #pragma unroll
    for (int n = 0; n < DSTATE; n++){ sP[c][n] = P[n]; sG[c][n] = G[n]; }
    __syncthreads();
    if (c >= off){
      #pragma unroll
      for (int n = 0; n < DSTATE; n++){
        float a1 = sP[c - off][n], b1 = sG[c - off][n];
        G[n] = P[n]*b1 + G[n];
        P[n] = P[n]*a1;
      }
    }
    __syncthreads();
  }
  #pragma unroll
  for (int n = 0; n < DSTATE; n++) sG[c][n] = G[n];
  __syncthreads();
  float4* Hp = (float4*)(Hin + ibase);
  if (c == 0){
    float4 z = make_float4(0.f,0.f,0.f,0.f);
    #pragma unroll
    for (int q = 0; q < 4; q++) Hp[q] = z;
  } else {
    #pragma unroll
    for (int q = 0; q < 4; q++)
      Hp[q] = make_float4(sG[c-1][q*4], sG[c-1][q*4+1], sG[c-1][q*4+2], sG[c-1][q*4+3]);
  }
}

// ---------------- Kernel 5: scan pass 3 — replay, emit oyT[l][k][d] ----------------
__global__ __launch_bounds__(384) void k_scan3(
    const float* __restrict__ xdbp,
    const float* __restrict__ xcR, const float* __restrict__ xcC,
    const float* __restrict__ dtw, const float* __restrict__ dtb,
    const float* __restrict__ alogs, const float* __restrict__ Dsv,
    const float* __restrict__ Hin, float* __restrict__ oyT){
  int k  = blockIdx.x >> 7;   // grid = 4*128
  int ch = blockIdx.x & 127;
  int l0 = ch * CHUNK;
  int t  = threadIdx.x;
  int d  = t >> 1, half = t & 1;
  __shared__ float sxd[CHUNK][NCP];      // unified aligned tile, branch-free copy
  __shared__ float sxc[CHUNK][DI + 1];
  {
    const float4* src = (const float4*)(xdbp + (size_t)(k*L + l0)*NCP);
    float4* dst = (float4*)&sxd[0][0];
    for (int j = t; j < CHUNK*NCP/4; j += 384) dst[j] = src[j];
  }
  const float* buf = (k & 1) ? xcC : xcR;
  int base = (k & 2) ? (L - l0 - CHUNK) : l0;
  for (int j = t; j < CHUNK*DI; j += 384){
    int row = j / DI, dd = j % DI;
    int i = (k & 2) ? (CHUNK - 1 - row) : row;
    sxc[i][dd] = buf[(size_t)(base + row)*DI + dd];
  }
  float wr[DTR];
  #pragma unroll
  for (int r = 0; r < DTR; r++) wr[r] = dtw[(k*DI + d)*DTR + r];
  float bb = dtb[k*DI + d];
  float A2[NS];
  const float* ap = alogs + (k*DI + d)*DSTATE + half*NS;
  #pragma unroll
  for (int j = 0; j < NS; j++) A2[j] = -__expf(ap[j]) * LOG2E;
  float h[NS];
  size_t hbase = (size_t)(k*NCHUNK + ch)*DI*DSTATE + t*NS;
  float4 h0 = ((const float4*)(Hin + hbase))[0];
  float4 h1 = ((const float4*)(Hin + hbase))[1];
  h[0]=h0.x; h[1]=h0.y; h[2]=h0.z; h[3]=h0.w;
  h[4]=h1.x; h[5]=h1.y; h[6]=h1.z; h[7]=h1.w;
  float Dv = Dsv[k*DI + d];
  __syncthreads();
  #pragma unroll 8
  for (int i = 0; i < CHUNK; i++){
    float xval = sxc[i][d];
    float dv = bb;
    #pragma unroll
    for (int r = 0; r < DTR; r++) dv += wr[r] * sxd[i][CT + r];
    dv = softplus_f(dv);
    float tv = dv * xval;
    float4 b0 = *(const float4*)&sxd[i][CB + half*8];
    float4 b1 = *(const float4*)&sxd[i][CB + half*8 + 4];
    float4 c0 = *(const float4*)&sxd[i][CC + half*8];
    float4 c1 = *(const float4*)&sxd[i][CC + half*8 + 4];
    float Bv[NS] = {b0.x,b0.y,b0.z,b0.w,b1.x,b1.y,b1.z,b1.w};
    float Cv[NS] = {c0.x,c0.y,c0.z,c0.w,c1.x,c1.y,c1.z,c1.w};
    float y = (half == 0) ? Dv * xval : 0.f;
    #pragma unroll
    for (int j = 0; j < NS; j++){
      float dA = exp2f(dv * A2[j]);
      h[j] = dA * h[j] + tv * Bv[j];
      y += h[j] * Cv[j];
    }
    y += __shfl_xor(y, 1);
    if (half == 0) oyT[(size_t)(l0 + i)*KD*DI + k*DI + d] = y;
  }
}

// ---------------- Kernel 6: k-sum + LayerNorm + silu(z)*y + out proj ----------------
__global__ void k_final(const float* __restrict__ oyT, const float* __restrict__ sz,
                        const float* __restrict__ g, const float* __restrict__ b,
                        const float* __restrict__ owT, float* __restrict__ out){
  int l = blockIdx.x, t = threadIdx.x;  // 192 threads
  __shared__ float ym[DI];
  __shared__ float part[DI];
  __shared__ float red[6];
  float y = 0.f;
  #pragma unroll
  for (int k = 0; k < KD; k++) y += oyT[(size_t)l*KD*DI + k*DI + t];
  float s = y, s2 = y*y;
  #pragma unroll
  for (int off = 32; off; off >>= 1){ s += __shfl_down(s, off); s2 += __shfl_down(s2, off); }
  int wave = t >> 6, lane = t & 63;
  if (lane == 0){ red[wave] = s; red[3 + wave] = s2; }
  __syncthreads();
  float S  = red[0] + red[1] + red[2];
  float SQ = red[3] + red[4] + red[5];
  float mu  = S * (1.f/DI);
  float var = SQ * (1.f/DI) - mu*mu;
  float yn = (y - mu) * rsqrtf(var + 1e-5f) * g[t] + b[t];
  ym[t] = yn * sz[(size_t)l*DI + t];
  __syncthreads();
  int o  = (t < DM) ? t : (t - DM);
  int d0 = (t < DM) ? 0 : DM;
  float acc = 0.f;
  #pragma unroll 8
  for (int dd = 0; dd < DM; dd++){
    int d = d0 + dd;
    acc += ym[d] * owT[d*DM + o];
  }
  part[t] = acc;
  __syncthreads();
  if (t < DM) out[l*DM + t] = part[t] + part[DM + t];
}

extern "C" void kernel_launch(void* const* d_in, const int* in_sizes, int n_in,
                              void* d_out, int out_size, void* d_ws, size_t ws_size,
                              hipStream_t stream){
  const float* x   = (const float*)d_in[0];
  const float* ipw = (const float*)d_in[1];
  const float* cw  = (const float*)d_in[2];
  const float* cb  = (const float*)d_in[3];
  const float* pw  = (const float*)d_in[4];
  const float* dtw = (const float*)d_in[5];
  const float* dtb = (const float*)d_in[6];
  const float* alg = (const float*)d_in[7];
  const float* Dsv = (const float*)d_in[8];
  const float* lng = (const float*)d_in[9];
  const float* lnb = (const float*)d_in[10];
  const float* ow  = (const float*)d_in[11];
  float* out = (float*)d_out;

  float* ws    = (float*)d_ws;
  float* x_    = ws; ws += L*DI;
  float* sz    = ws; ws += L*DI;
  float* xcR   = ws; ws += L*DI;
  float* xcC   = ws; ws += L*DI;
  float* xdbp  = ws; ws += (size_t)KD*L*NCP;
  float* Pb    = ws; ws += (size_t)KD*NCHUNK*DI*DSTATE;
  float* Gb    = ws; ws += (size_t)KD*NCHUNK*DI*DSTATE;
  float* Hin   = ws; ws += (size_t)KD*NCHUNK*DI*DSTATE;
  float* oyT   = ws; ws += (size_t)L*KD*DI;
  float* ipwT  = ws; ws += 384*DM;
  float* pwT   = ws; ws += KD*DI*NCP;
  float* owT   = ws; ws += DM*DI;

  int prep_tot = 384*DM + KD*NC*DI + DM*DI + KD*DI*2;
  k_prep<<<(prep_tot + 255)/256, 256, 0, stream>>>(ipw, pw, ow, ipwT, pwT, owT);
  k_inproj<<<L/TL, 384, 0, stream>>>(x, ipwT, x_, sz);
  k_conv<<<(L*DI + 383)/384, 384, 0, stream>>>(x_, cw, cb, xcR, xcC);
  k_xs1<<<KD*NCHUNK, 384, 0, stream>>>(xcR, xcC, pwT, dtw, dtb, alg, xdbp, Pb, Gb);
  k_scan2<<<KD*DI, NCHUNK, 0, stream>>>(Pb, Gb, Hin);
  k_scan3<<<KD*NCHUNK, 384, 0, stream>>>(xdbp, xcR, xcC, dtw, dtb, alg, Dsv, Hin, oyT);
  k_final<<<L, DI, 0, stream>>>(oyT, sz, lng, lnb, owT, out);
}